// Round 10
// baseline (238.144 us; speedup 1.0000x reference)
//
#include <hip/hip_runtime.h>
#include <hip/hip_bf16.h>

typedef __attribute__((ext_vector_type(8))) short bf16x8;
typedef __attribute__((ext_vector_type(4))) float f32x4;

__device__ inline ushort f2bf(float f) {
    union { float f; unsigned u; } x; x.f = f;
    unsigned u = x.u;
    u += 0x7fffu + ((u >> 16) & 1u);   // round-to-nearest-even
    return (ushort)(u >> 16);
}

// feat (B,C,H,W) f32 -> featT (B,98,98,C) bf16, zero-padded 1-px border
__global__ void prep_feat_k(const float* __restrict__ feat, ushort* __restrict__ featT) {
    int idx = blockIdx.x * 256 + threadIdx.x;
    if (idx >= 2 * 98 * 98 * 64) return;
    int c = idx & 63;
    int rest = idx >> 6;
    int x = rest % 98; rest /= 98;
    int y = rest % 98;
    int b = rest / 98;
    ushort v = 0;
    if (x >= 1 && x <= 96 && y >= 1 && y <= 96)
        v = f2bf(feat[((b * 64 + c) * 96 + (y - 1)) * 96 + (x - 1)]);
    featT[idx] = v;
}

// Weights f32 (K,N) -> bf16 B-fragment layout [nt][kt][lane][8]
__global__ void prep_w_k(const float* __restrict__ W, ushort* __restrict__ Wp,
                         int NT, int NKT, int Nstride, int mode) {
    int idx = blockIdx.x * 256 + threadIdx.x;
    if (idx >= NT * NKT * 64) return;
    int lane = idx & 63;
    int kt = (idx >> 6) % NKT;
    int nt = idx / (64 * NKT);
    int n = nt * 16 + (lane & 15);
    int kbase = kt * 32 + (lane >> 4) * 8;
    ushort o[8];
    #pragma unroll
    for (int i = 0; i < 8; ++i) {
        int k = kbase + i;
        float v = 0.0f;
        if (mode == 0) {
            if (k < 576) { int tap = k >> 6, c = k & 63; v = W[(c * 9 + tap) * Nstride + n]; }
            else if (k < 580) v = W[k * Nstride + n];
        } else if (mode == 1) {
            v = W[k * Nstride + n];
        } else {
            v = (n == 0) ? W[k] : 0.0f;
        }
        o[i] = f2bf(v);
    }
    *reinterpret_cast<uint4*>(Wp + (size_t)idx * 8) = *reinterpret_cast<const uint4*>(o);
}

// Activations in MFMA A-fragment layout: line = rt*8+kt, position p=lane.
// Physical slot = p ^ ((p>>4)&3)  (round-9 measured: conflicts 10.9M -> 2.5M).
__device__ __forceinline__ int SW(int p) { return p ^ ((p >> 4) & 3); }

__global__ __launch_bounds__(256, 4) void liif_main(
    const float* __restrict__ coord, const float* __restrict__ cell,
    const ushort* __restrict__ featT,
    const ushort* __restrict__ W0p, const ushort* __restrict__ W1p,
    const ushort* __restrict__ W2p, const ushort* __restrict__ W3p,
    const ushort* __restrict__ W4p,
    const float* __restrict__ b0, const float* __restrict__ b1,
    const float* __restrict__ b2, const float* __restrict__ b3,
    const float* __restrict__ b4, float* __restrict__ out)
{
    // act layout: ((rt*8 + kt)*64 + phys)*8   rt 0..3, kt 0..7   (32768 B)
    __shared__ ushort buf[4 * 8 * 64 * 8];
    __shared__ float pred_lds[64];
    __shared__ float area_lds[64];

    const int t = threadIdx.x;
    const int lane = t & 63;
    const int w = t >> 6;
    const int g = lane >> 4;
    const int l15 = lane & 15;
    const int swl = SW(lane);

    // ---------------- gather setup: minimal persistent state ----------------
    const ushort* p0;
    ushort* g_lds;
    uint ex01, ex23;
    {
        const int r = t >> 2, sub = t & 3;          // r 0..63
        const int qi = r >> 2, s = r & 3;           // row = 4*qi + shift s
        const int gq = blockIdx.x * 16 + qi;        // = b*Q + q
        const int bidx = gq >> 15;                  // Q = 32768
        const float vx = (s & 2) ? 1.0f : -1.0f;
        const float vy = (s & 1) ? 1.0f : -1.0f;
        const float rxf = (float)(1.0 / 96.0);
        const float lo = (float)(-1.0 + 1e-6);
        const float hi = (float)(1.0 - 1e-6);
        float c0 = coord[gq * 2 + 0], c1 = coord[gq * 2 + 1];
        float cl0 = cell[gq * 2 + 0], cl1 = cell[gq * 2 + 1];
        float sc0 = fminf(fmaxf(__fadd_rn(__fadd_rn(c0, vx * rxf), 1e-6f), lo), hi);
        float sc1 = fminf(fmaxf(__fadd_rn(__fadd_rn(c1, vy * rxf), 1e-6f), lo), hi);
        float fy = __fmul_rn(__fadd_rn(__fmul_rn(__fadd_rn(sc0, 1.0f), 96.0f), -1.0f), 0.5f);
        float fx = __fmul_rn(__fadd_rn(__fmul_rn(__fadd_rn(sc1, 1.0f), 96.0f), -1.0f), 0.5f);
        int iy = (int)rintf(fy); iy = iy < 0 ? 0 : (iy > 95 ? 95 : iy);
        int ix = (int)rintf(fx); ix = ix < 0 ? 0 : (ix > 95 ? 95 : ix);
        float qc0 = (iy + 0.5f) * (float)(2.0 / 96.0) - 1.0f;
        float qc1 = (ix + 0.5f) * (float)(2.0 / 96.0) - 1.0f;
        float rel0 = (c0 - qc0) * 96.0f;
        float rel1 = (c1 - qc1) * 96.0f;
        if (sub == 0) {
            area_lds[r] = fabsf(rel0 * rel1) + 1e-9f;
            asm("v_cvt_pk_bf16_f32 %0, %1, %2" : "=v"(ex01) : "v"(rel0), "v"(rel1));
            float rc0 = cl0 * 96.0f, rc1 = cl1 * 96.0f;
            asm("v_cvt_pk_bf16_f32 %0, %1, %2" : "=v"(ex23) : "v"(rc0), "v"(rc1));
        } else {
            ex01 = 0; ex23 = 0;
        }
        const int g_rt = r >> 4;
        const int g_sw = SW((r & 15) + (sub << 4));
        p0 = featT + (size_t)bidx * 98 * 98 * 64 + (iy * 98 + ix) * 64 + sub * 8;
        g_lds = buf + (g_rt * 8 * 64 + g_sw) * 8;   // + LINE*512 immediates
    }

    // act-store bases: value v_j of frag (rt,ct) -> phys 4g + 16m + (j2^hi8),
    // m = 2(ct&1)+hi8, j2 = j^(2(ct&1)); even j2 -> spE, odd -> spO.
    const int hi8 = l15 >> 3;
    ushort* sp  = buf + w * 1024 + g * 32 + hi8 * 128 + (l15 & 7);
    ushort* spE = sp + 8 * hi8;
    ushort* spO = sp - 8 * hi8;

    f32x4 acc[4][4];

    auto store_acts = [&]() {
        #pragma unroll
        for (int ct = 0; ct < 4; ++ct)
            #pragma unroll
            for (int rt = 0; rt < 4; ++rt) {
                float v0 = fmaxf(acc[rt][ct][0], 0.0f);
                float v1 = fmaxf(acc[rt][ct][1], 0.0f);
                float v2 = fmaxf(acc[rt][ct][2], 0.0f);
                float v3 = fmaxf(acc[rt][ct][3], 0.0f);
                uint p01, p23;
                asm("v_cvt_pk_bf16_f32 %0, %1, %2" : "=v"(p01) : "v"(v0), "v"(v1));
                asm("v_cvt_pk_bf16_f32 %0, %1, %2" : "=v"(p23) : "v"(v2), "v"(v3));
                const int off = rt * 4096 + (ct >> 1) * 512 + (ct & 1) * 256;
                if ((ct & 1) == 0) {
                    spE[off + 0]  = (ushort)p01;
                    spO[off + 8]  = (ushort)(p01 >> 16);
                    spE[off + 16] = (ushort)p23;
                    spO[off + 24] = (ushort)(p23 >> 16);
                } else {
                    spE[off + 16] = (ushort)p01;
                    spO[off + 24] = (ushort)(p01 >> 16);
                    spE[off + 0]  = (ushort)p23;
                    spO[off + 8]  = (ushort)(p23 >> 16);
                }
            }
    };

    auto init_acc = [&](const float* bias) {
        #pragma unroll
        for (int ct = 0; ct < 4; ++ct) {
            float bv = bias[(w * 4 + ct) * 16 + l15];
            #pragma unroll
            for (int rt = 0; rt < 4; ++rt) {
                acc[rt][ct][0] = bv; acc[rt][ct][1] = bv;
                acc[rt][ct][2] = bv; acc[rt][ct][3] = bv;
            }
        }
    };

#define LOADW0(DST, KT) do { _Pragma("unroll")                                   \
        for (int ct_ = 0; ct_ < 4; ++ct_)                                        \
            DST[ct_] = *reinterpret_cast<const bf16x8*>(                         \
                W0p + (((size_t)(w * 4 + ct_) * 19 + (KT)) * 64 + lane) * 8);    \
    } while (0)
#define LOADWX(DST, WP, KT) do { _Pragma("unroll")                               \
        for (int ct_ = 0; ct_ < 4; ++ct_)                                        \
            DST[ct_] = *reinterpret_cast<const bf16x8*>(                         \
                (WP) + (((size_t)(w * 4 + ct_) * 8 + (KT)) * 64 + lane) * 8);    \
    } while (0)
#define MFMA_LINE(BFR, LINE) do { _Pragma("unroll")                              \
        for (int rt_ = 0; rt_ < 4; ++rt_) {                                      \
            bf16x8 a_ = *reinterpret_cast<const bf16x8*>(                        \
                buf + ((rt_ * 8 + (LINE)) * 64 + swl) * 8);                      \
            _Pragma("unroll")                                                    \
            for (int ct_ = 0; ct_ < 4; ++ct_)                                    \
                acc[rt_][ct_] = __builtin_amdgcn_mfma_f32_16x16x32_bf16(         \
                    a_, BFR[ct_], acc[rt_][ct_], 0, 0, 0);                       \
        } } while (0)
#define G1(KT, LINE) do {                                                        \
        constexpr int tap_ = (KT) >> 1;                                          \
        constexpr int coff_ = ((tap_ / 3) * 98 + (tap_ % 3)) * 64 + ((KT) & 1) * 32; \
        *reinterpret_cast<uint4*>(g_lds + (LINE) * 512) =                        \
            *reinterpret_cast<const uint4*>(p0 + coff_);                         \
    } while (0)

    // ---------------- layer 1: 3 phases (8+8+3), wA/wB ping-pong, no copies ----------------
    init_acc(b0);
    bf16x8 wA[4], wB[4];
    G1(0, 0); G1(1, 1); G1(2, 2); G1(3, 3); G1(4, 4); G1(5, 5); G1(6, 6); G1(7, 7);
    LOADW0(wA, 0); LOADW0(wB, 1);
    __syncthreads();
    __builtin_amdgcn_s_setprio(1);
    MFMA_LINE(wA, 0); LOADW0(wA, 2);
    MFMA_LINE(wB, 1); LOADW0(wB, 3);
    MFMA_LINE(wA, 2); LOADW0(wA, 4);
    MFMA_LINE(wB, 3); LOADW0(wB, 5);
    MFMA_LINE(wA, 4); LOADW0(wA, 6);
    MFMA_LINE(wB, 5); LOADW0(wB, 7);
    MFMA_LINE(wA, 6); LOADW0(wA, 8);
    MFMA_LINE(wB, 7); LOADW0(wB, 9);
    __builtin_amdgcn_s_setprio(0);
    __syncthreads();
    G1(8, 0); G1(9, 1); G1(10, 2); G1(11, 3); G1(12, 4); G1(13, 5); G1(14, 6); G1(15, 7);
    __syncthreads();
    __builtin_amdgcn_s_setprio(1);
    MFMA_LINE(wA, 0); LOADW0(wA, 10);
    MFMA_LINE(wB, 1); LOADW0(wB, 11);
    MFMA_LINE(wA, 2); LOADW0(wA, 12);
    MFMA_LINE(wB, 3); LOADW0(wB, 13);
    MFMA_LINE(wA, 4); LOADW0(wA, 14);
    MFMA_LINE(wB, 5); LOADW0(wB, 15);
    MFMA_LINE(wA, 6); LOADW0(wA, 16);
    MFMA_LINE(wB, 7); LOADW0(wB, 17);
    __builtin_amdgcn_s_setprio(0);
    __syncthreads();
    G1(16, 0); G1(17, 1);
    *reinterpret_cast<uint4*>(g_lds + 2 * 512) = make_uint4(ex01, ex23, 0, 0);
    __syncthreads();
    __builtin_amdgcn_s_setprio(1);
    MFMA_LINE(wA, 0); LOADW0(wA, 18);
    MFMA_LINE(wB, 1);
    MFMA_LINE(wA, 2);
    __builtin_amdgcn_s_setprio(0);
    __syncthreads();

    // ---------------- layers 2..4: W preload above stores; own-kt mfma pre-barrier ----------------
    #pragma unroll 1
    for (int layer = 0; layer < 3; ++layer) {
        const ushort* Wp = (layer == 0) ? W1p : (layer == 1) ? W2p : W3p;
        const float* bias = (layer == 0) ? b1 : (layer == 1) ? b2 : b3;
        const int k0 = 2 * w;
        LOADWX(wA, Wp, k0);                  // L2 latency hides under store_acts
        LOADWX(wB, Wp, k0 + 1);
        store_acts();
        init_acc(bias);
        // own col-tiles provide A-lines 2w, 2w+1: same-wave DS order safe
        __builtin_amdgcn_s_setprio(1);
        MFMA_LINE(wA, k0);     LOADWX(wA, Wp, (k0 + 2) & 7);
        MFMA_LINE(wB, k0 + 1); LOADWX(wB, Wp, (k0 + 3) & 7);
        __builtin_amdgcn_s_setprio(0);
        __syncthreads();
        __builtin_amdgcn_s_setprio(1);
        MFMA_LINE(wA, (k0 + 2) & 7); LOADWX(wA, Wp, (k0 + 4) & 7);
        MFMA_LINE(wB, (k0 + 3) & 7); LOADWX(wB, Wp, (k0 + 5) & 7);
        MFMA_LINE(wA, (k0 + 4) & 7); LOADWX(wA, Wp, (k0 + 6) & 7);
        MFMA_LINE(wB, (k0 + 5) & 7); LOADWX(wB, Wp, (k0 + 7) & 7);
        MFMA_LINE(wA, (k0 + 6) & 7);
        MFMA_LINE(wB, (k0 + 7) & 7);
        __builtin_amdgcn_s_setprio(0);
        __syncthreads();
    }
    // layer-4 acts
    store_acts();
    __syncthreads();

    // ---------------- layer 5: 256 -> 1 (wave w handles row-tile w) ----------------
    {
        float b4v = b4[0];
        f32x4 a5;
        a5[0] = b4v; a5[1] = b4v; a5[2] = b4v; a5[3] = b4v;
        #pragma unroll
        for (int kt = 0; kt < 8; ++kt) {
            bf16x8 bb = *reinterpret_cast<const bf16x8*>(W4p + ((size_t)kt * 64 + lane) * 8);
            bf16x8 aa = *reinterpret_cast<const bf16x8*>(buf + ((w * 8 + kt) * 64 + swl) * 8);
            a5 = __builtin_amdgcn_mfma_f32_16x16x32_bf16(aa, bb, a5, 0, 0, 0);
        }
        if (l15 == 0) {
            #pragma unroll
            for (int j = 0; j < 4; ++j)
                pred_lds[w * 16 + (g << 2) + j] = a5[j];
        }
    }
    __syncthreads();

    // ---------------- local-ensemble combine (diagonal area swap) ----------------
    if (t < 16) {
        int oq = blockIdx.x * 16 + t;
        float p0v = pred_lds[t * 4 + 0], p1v = pred_lds[t * 4 + 1];
        float p2v = pred_lds[t * 4 + 2], p3v = pred_lds[t * 4 + 3];
        float a0 = area_lds[t * 4 + 0], a1 = area_lds[t * 4 + 1];
        float a2 = area_lds[t * 4 + 2], a3 = area_lds[t * 4 + 3];
        float tot = a0 + a1 + a2 + a3;
        out[oq] = (p0v * a3 + p1v * a2 + p2v * a1 + p3v * a0) / tot;
    }
#undef G1
#undef LOADW0
#undef LOADWX
#undef MFMA_LINE
}

extern "C" void kernel_launch(void* const* d_in, const int* in_sizes, int n_in,
                              void* d_out, int out_size, void* d_ws, size_t ws_size,
                              hipStream_t stream) {
    const float* feat  = (const float*)d_in[0];
    const float* coord = (const float*)d_in[1];
    const float* cell  = (const float*)d_in[2];
    const float* W0 = (const float*)d_in[3];
    const float* b0 = (const float*)d_in[4];
    const float* W1 = (const float*)d_in[5];
    const float* b1 = (const float*)d_in[6];
    const float* W2 = (const float*)d_in[7];
    const float* b2 = (const float*)d_in[8];
    const float* W3 = (const float*)d_in[9];
    const float* b3 = (const float*)d_in[10];
    const float* W4 = (const float*)d_in[11];
    const float* b4 = (const float*)d_in[12];
    float* out = (float*)d_out;

    ushort* featT = (ushort*)d_ws;          // 2*98*98*64      = 1229312 elems
    ushort* W0p = featT + 1229312;          // 16*19*64*8      = 155648
    ushort* W1p = W0p + 155648;             // 16*8*64*8       = 65536
    ushort* W2p = W1p + 65536;
    ushort* W3p = W2p + 65536;
    ushort* W4p = W3p + 65536;              // 1*8*64*8        = 4096

    prep_feat_k<<<4802, 256, 0, stream>>>(feat, featT);
    prep_w_k<<<76, 256, 0, stream>>>(W0, W0p, 16, 19, 256, 0);
    prep_w_k<<<32, 256, 0, stream>>>(W1, W1p, 16, 8, 256, 1);
    prep_w_k<<<32, 256, 0, stream>>>(W2, W2p, 16, 8, 256, 1);
    prep_w_k<<<32, 256, 0, stream>>>(W3, W3p, 16, 8, 256, 1);
    prep_w_k<<<2, 256, 0, stream>>>(W4, W4p, 1, 8, 1, 2);
    liif_main<<<4096, 256, 0, stream>>>(coord, cell, featT, W0p, W1p, W2p, W3p, W4p,
                                        b0, b1, b2, b3, b4, out);
}

// Round 11
// 203.037 us; speedup vs baseline: 1.1729x; 1.1729x over previous
//
#include <hip/hip_runtime.h>
#include <hip/hip_bf16.h>

typedef __attribute__((ext_vector_type(8))) short bf16x8;
typedef __attribute__((ext_vector_type(4))) float f32x4;

__device__ inline ushort f2bf(float f) {
    union { float f; unsigned u; } x; x.f = f;
    unsigned u = x.u;
    u += 0x7fffu + ((u >> 16) & 1u);   // round-to-nearest-even
    return (ushort)(u >> 16);
}

// feat (B,C,H,W) f32 -> featT (B,98,98,C) bf16, zero-padded 1-px border
__global__ void prep_feat_k(const float* __restrict__ feat, ushort* __restrict__ featT) {
    int idx = blockIdx.x * 256 + threadIdx.x;
    if (idx >= 2 * 98 * 98 * 64) return;
    int c = idx & 63;
    int rest = idx >> 6;
    int x = rest % 98; rest /= 98;
    int y = rest % 98;
    int b = rest / 98;
    ushort v = 0;
    if (x >= 1 && x <= 96 && y >= 1 && y <= 96)
        v = f2bf(feat[((b * 64 + c) * 96 + (y - 1)) * 96 + (x - 1)]);
    featT[idx] = v;
}

// Weights f32 (K,N) -> bf16 B-fragment layout [nt][kt][lane][8]
__global__ void prep_w_k(const float* __restrict__ W, ushort* __restrict__ Wp,
                         int NT, int NKT, int Nstride, int mode) {
    int idx = blockIdx.x * 256 + threadIdx.x;
    if (idx >= NT * NKT * 64) return;
    int lane = idx & 63;
    int kt = (idx >> 6) % NKT;
    int nt = idx / (64 * NKT);
    int n = nt * 16 + (lane & 15);
    int kbase = kt * 32 + (lane >> 4) * 8;
    ushort o[8];
    #pragma unroll
    for (int i = 0; i < 8; ++i) {
        int k = kbase + i;
        float v = 0.0f;
        if (mode == 0) {
            if (k < 576) { int tap = k >> 6, c = k & 63; v = W[(c * 9 + tap) * Nstride + n]; }
            else if (k < 580) v = W[k * Nstride + n];
        } else if (mode == 1) {
            v = W[k * Nstride + n];
        } else {
            v = (n == 0) ? W[k] : 0.0f;
        }
        o[i] = f2bf(v);
    }
    *reinterpret_cast<uint4*>(Wp + (size_t)idx * 8) = *reinterpret_cast<const uint4*>(o);
}

// Activations in MFMA A-fragment layout: line = rt*8+kt, position p=lane.
// Physical slot = p ^ ((p>>4)&3)  (round-9 measured: conflicts 10.9M -> 2.5M).
__device__ __forceinline__ int SW(int p) { return p ^ ((p >> 4) & 3); }

__global__ __launch_bounds__(256, 3) void liif_main(
    const float* __restrict__ coord, const float* __restrict__ cell,
    const ushort* __restrict__ featT,
    const ushort* __restrict__ W0p, const ushort* __restrict__ W1p,
    const ushort* __restrict__ W2p, const ushort* __restrict__ W3p,
    const ushort* __restrict__ W4p,
    const float* __restrict__ b0, const float* __restrict__ b1,
    const float* __restrict__ b2, const float* __restrict__ b3,
    const float* __restrict__ b4, float* __restrict__ out)
{
    // act layout: ((rt*8 + kt)*64 + phys)*8   rt 0..3, kt 0..7   (32768 B)
    __shared__ ushort buf[4 * 8 * 64 * 8];
    __shared__ float pred_lds[64];
    __shared__ float area_lds[64];

    const int t = threadIdx.x;
    const int lane = t & 63;
    const int w = t >> 6;
    const int g = lane >> 4;
    const int l15 = lane & 15;
    const int swl = SW(lane);

    // ---------------- gather setup: minimal persistent state ----------------
    const ushort* p0;
    ushort* g_lds;
    uint ex01, ex23;
    {
        const int r = t >> 2, sub = t & 3;          // r 0..63
        const int qi = r >> 2, s = r & 3;           // row = 4*qi + shift s
        const int gq = blockIdx.x * 16 + qi;        // = b*Q + q
        const int bidx = gq >> 15;                  // Q = 32768
        const float vx = (s & 2) ? 1.0f : -1.0f;
        const float vy = (s & 1) ? 1.0f : -1.0f;
        const float rxf = (float)(1.0 / 96.0);
        const float lo = (float)(-1.0 + 1e-6);
        const float hi = (float)(1.0 - 1e-6);
        float c0 = coord[gq * 2 + 0], c1 = coord[gq * 2 + 1];
        float cl0 = cell[gq * 2 + 0], cl1 = cell[gq * 2 + 1];
        float sc0 = fminf(fmaxf(__fadd_rn(__fadd_rn(c0, vx * rxf), 1e-6f), lo), hi);
        float sc1 = fminf(fmaxf(__fadd_rn(__fadd_rn(c1, vy * rxf), 1e-6f), lo), hi);
        float fy = __fmul_rn(__fadd_rn(__fmul_rn(__fadd_rn(sc0, 1.0f), 96.0f), -1.0f), 0.5f);
        float fx = __fmul_rn(__fadd_rn(__fmul_rn(__fadd_rn(sc1, 1.0f), 96.0f), -1.0f), 0.5f);
        int iy = (int)rintf(fy); iy = iy < 0 ? 0 : (iy > 95 ? 95 : iy);
        int ix = (int)rintf(fx); ix = ix < 0 ? 0 : (ix > 95 ? 95 : ix);
        float qc0 = (iy + 0.5f) * (float)(2.0 / 96.0) - 1.0f;
        float qc1 = (ix + 0.5f) * (float)(2.0 / 96.0) - 1.0f;
        float rel0 = (c0 - qc0) * 96.0f;
        float rel1 = (c1 - qc1) * 96.0f;
        if (sub == 0) {
            area_lds[r] = fabsf(rel0 * rel1) + 1e-9f;
            asm("v_cvt_pk_bf16_f32 %0, %1, %2" : "=v"(ex01) : "v"(rel0), "v"(rel1));
            float rc0 = cl0 * 96.0f, rc1 = cl1 * 96.0f;
            asm("v_cvt_pk_bf16_f32 %0, %1, %2" : "=v"(ex23) : "v"(rc0), "v"(rc1));
        } else {
            ex01 = 0; ex23 = 0;
        }
        const int g_rt = r >> 4;
        const int g_sw = SW((r & 15) + (sub << 4));
        p0 = featT + (size_t)bidx * 98 * 98 * 64 + (iy * 98 + ix) * 64 + sub * 8;
        g_lds = buf + (g_rt * 8 * 64 + g_sw) * 8;   // + LINE*512 immediates
    }

    // act-store bases: value v_j of frag (rt,ct) -> phys 4g + 16m + (j2^hi8),
    // m = 2(ct&1)+hi8, j2 = j^(2(ct&1)); even j2 -> spE, odd -> spO.
    const int hi8 = l15 >> 3;
    ushort* sp  = buf + w * 1024 + g * 32 + hi8 * 128 + (l15 & 7);
    ushort* spE = sp + 8 * hi8;
    ushort* spO = sp - 8 * hi8;

    f32x4 acc[4][4];

    auto store_acts = [&]() {
        #pragma unroll
        for (int ct = 0; ct < 4; ++ct)
            #pragma unroll
            for (int rt = 0; rt < 4; ++rt) {
                float v0 = fmaxf(acc[rt][ct][0], 0.0f);
                float v1 = fmaxf(acc[rt][ct][1], 0.0f);
                float v2 = fmaxf(acc[rt][ct][2], 0.0f);
                float v3 = fmaxf(acc[rt][ct][3], 0.0f);
                uint p01, p23;
                asm("v_cvt_pk_bf16_f32 %0, %1, %2" : "=v"(p01) : "v"(v0), "v"(v1));
                asm("v_cvt_pk_bf16_f32 %0, %1, %2" : "=v"(p23) : "v"(v2), "v"(v3));
                const int off = rt * 4096 + (ct >> 1) * 512 + (ct & 1) * 256;
                if ((ct & 1) == 0) {
                    spE[off + 0]  = (ushort)p01;
                    spO[off + 8]  = (ushort)(p01 >> 16);
                    spE[off + 16] = (ushort)p23;
                    spO[off + 24] = (ushort)(p23 >> 16);
                } else {
                    spE[off + 16] = (ushort)p01;
                    spO[off + 24] = (ushort)(p01 >> 16);
                    spE[off + 0]  = (ushort)p23;
                    spO[off + 8]  = (ushort)(p23 >> 16);
                }
            }
    };

    auto init_acc = [&](const float* bias) {
        #pragma unroll
        for (int ct = 0; ct < 4; ++ct) {
            float bv = bias[(w * 4 + ct) * 16 + l15];
            #pragma unroll
            for (int rt = 0; rt < 4; ++rt) {
                acc[rt][ct][0] = bv; acc[rt][ct][1] = bv;
                acc[rt][ct][2] = bv; acc[rt][ct][3] = bv;
            }
        }
    };

#define LOADW0(DST, KT) do { _Pragma("unroll")                                   \
        for (int ct_ = 0; ct_ < 4; ++ct_)                                        \
            DST[ct_] = *reinterpret_cast<const bf16x8*>(                         \
                W0p + (((size_t)(w * 4 + ct_) * 19 + (KT)) * 64 + lane) * 8);    \
    } while (0)
#define LOADWX(DST, WP, KT) do { _Pragma("unroll")                               \
        for (int ct_ = 0; ct_ < 4; ++ct_)                                        \
            DST[ct_] = *reinterpret_cast<const bf16x8*>(                         \
                (WP) + (((size_t)(w * 4 + ct_) * 8 + (KT)) * 64 + lane) * 8);    \
    } while (0)
#define MFMA_LINE(BFR, LINE) do { _Pragma("unroll")                              \
        for (int rt_ = 0; rt_ < 4; ++rt_) {                                      \
            bf16x8 a_ = *reinterpret_cast<const bf16x8*>(                        \
                buf + ((rt_ * 8 + (LINE)) * 64 + swl) * 8);                      \
            _Pragma("unroll")                                                    \
            for (int ct_ = 0; ct_ < 4; ++ct_)                                    \
                acc[rt_][ct_] = __builtin_amdgcn_mfma_f32_16x16x32_bf16(         \
                    a_, BFR[ct_], acc[rt_][ct_], 0, 0, 0);                       \
        } } while (0)
#define G1(KT, LINE) do {                                                        \
        constexpr int tap_ = (KT) >> 1;                                          \
        constexpr int coff_ = ((tap_ / 3) * 98 + (tap_ % 3)) * 64 + ((KT) & 1) * 32; \
        *reinterpret_cast<uint4*>(g_lds + (LINE) * 512) =                        \
            *reinterpret_cast<const uint4*>(p0 + coff_);                         \
    } while (0)

    // ---------------- layer 1: 3 phases (8 + 8 + 3 k-tiles), W prefetched ----------------
    init_acc(b0);
    bf16x8 cur[4], nxt[4];
    G1(0, 0); G1(1, 1); G1(2, 2); G1(3, 3); G1(4, 4); G1(5, 5); G1(6, 6); G1(7, 7);
    LOADW0(cur, 0);
    __syncthreads();
    __builtin_amdgcn_s_setprio(1);
    #pragma unroll 1
    for (int i = 0; i < 8; ++i) {
        if (i < 7) LOADW0(nxt, i + 1);
        MFMA_LINE(cur, i);
        #pragma unroll
        for (int c_ = 0; c_ < 4; ++c_) cur[c_] = nxt[c_];
    }
    __builtin_amdgcn_s_setprio(0);
    __syncthreads();
    G1(8, 0); G1(9, 1); G1(10, 2); G1(11, 3); G1(12, 4); G1(13, 5); G1(14, 6); G1(15, 7);
    LOADW0(cur, 8);
    __syncthreads();
    __builtin_amdgcn_s_setprio(1);
    #pragma unroll 1
    for (int i = 0; i < 8; ++i) {
        if (i < 7) LOADW0(nxt, 9 + i);
        MFMA_LINE(cur, i);
        #pragma unroll
        for (int c_ = 0; c_ < 4; ++c_) cur[c_] = nxt[c_];
    }
    __builtin_amdgcn_s_setprio(0);
    __syncthreads();
    G1(16, 0); G1(17, 1);
    *reinterpret_cast<uint4*>(g_lds + 2 * 512) = make_uint4(ex01, ex23, 0, 0);
    LOADW0(cur, 16);
    __syncthreads();
    __builtin_amdgcn_s_setprio(1);
    LOADW0(nxt, 17);
    MFMA_LINE(cur, 0);
    #pragma unroll
    for (int c_ = 0; c_ < 4; ++c_) cur[c_] = nxt[c_];
    LOADW0(nxt, 18);
    MFMA_LINE(cur, 1);
    #pragma unroll
    for (int c_ = 0; c_ < 4; ++c_) cur[c_] = nxt[c_];
    MFMA_LINE(cur, 2);
    __builtin_amdgcn_s_setprio(0);
    __syncthreads();

    // ---------------- layers 2..4: store -> own-kt mfma -> barrier -> rest ----------------
    #pragma unroll 1
    for (int layer = 0; layer < 3; ++layer) {
        store_acts();
        const ushort* Wp = (layer == 0) ? W1p : (layer == 1) ? W2p : W3p;
        const float* bias = (layer == 0) ? b1 : (layer == 1) ? b2 : b3;
        init_acc(bias);
        // own col-tiles provide A for kt = 2w, 2w+1: same-wave DS order makes
        // own write->read safe; overlaps other waves' stores
        LOADWX(cur, Wp, 2 * w);
        __builtin_amdgcn_s_setprio(1);
        LOADWX(nxt, Wp, 2 * w + 1);
        MFMA_LINE(cur, 2 * w);
        #pragma unroll
        for (int c_ = 0; c_ < 4; ++c_) cur[c_] = nxt[c_];
        LOADWX(nxt, Wp, (2 * w + 2) & 7);
        MFMA_LINE(cur, 2 * w + 1);
        __builtin_amdgcn_s_setprio(0);
        __syncthreads();
        __builtin_amdgcn_s_setprio(1);
        #pragma unroll 1
        for (int i = 2; i < 8; ++i) {
            #pragma unroll
            for (int c_ = 0; c_ < 4; ++c_) cur[c_] = nxt[c_];
            if (i < 7) LOADWX(nxt, Wp, (2 * w + i + 1) & 7);
            MFMA_LINE(cur, (2 * w + i) & 7);
        }
        __builtin_amdgcn_s_setprio(0);
        __syncthreads();
    }
    // layer-4 acts
    store_acts();
    __syncthreads();

    // ---------------- layer 5: 256 -> 1 (wave w handles row-tile w) ----------------
    {
        float b4v = b4[0];
        f32x4 a5;
        a5[0] = b4v; a5[1] = b4v; a5[2] = b4v; a5[3] = b4v;
        #pragma unroll
        for (int kt = 0; kt < 8; ++kt) {
            bf16x8 bb = *reinterpret_cast<const bf16x8*>(W4p + ((size_t)kt * 64 + lane) * 8);
            bf16x8 aa = *reinterpret_cast<const bf16x8*>(buf + ((w * 8 + kt) * 64 + swl) * 8);
            a5 = __builtin_amdgcn_mfma_f32_16x16x32_bf16(aa, bb, a5, 0, 0, 0);
        }
        if (l15 == 0) {
            #pragma unroll
            for (int j = 0; j < 4; ++j)
                pred_lds[w * 16 + (g << 2) + j] = a5[j];
        }
    }
    __syncthreads();

    // ---------------- local-ensemble combine (diagonal area swap) ----------------
    if (t < 16) {
        int oq = blockIdx.x * 16 + t;
        float p0v = pred_lds[t * 4 + 0], p1v = pred_lds[t * 4 + 1];
        float p2v = pred_lds[t * 4 + 2], p3v = pred_lds[t * 4 + 3];
        float a0 = area_lds[t * 4 + 0], a1 = area_lds[t * 4 + 1];
        float a2 = area_lds[t * 4 + 2], a3 = area_lds[t * 4 + 3];
        float tot = a0 + a1 + a2 + a3;
        out[oq] = (p0v * a3 + p1v * a2 + p2v * a1 + p3v * a0) / tot;
    }
#undef G1
#undef LOADW0
#undef LOADWX
#undef MFMA_LINE
}

extern "C" void kernel_launch(void* const* d_in, const int* in_sizes, int n_in,
                              void* d_out, int out_size, void* d_ws, size_t ws_size,
                              hipStream_t stream) {
    const float* feat  = (const float*)d_in[0];
    const float* coord = (const float*)d_in[1];
    const float* cell  = (const float*)d_in[2];
    const float* W0 = (const float*)d_in[3];
    const float* b0 = (const float*)d_in[4];
    const float* W1 = (const float*)d_in[5];
    const float* b1 = (const float*)d_in[6];
    const float* W2 = (const float*)d_in[7];
    const float* b2 = (const float*)d_in[8];
    const float* W3 = (const float*)d_in[9];
    const float* b3 = (const float*)d_in[10];
    const float* W4 = (const float*)d_in[11];
    const float* b4 = (const float*)d_in[12];
    float* out = (float*)d_out;

    ushort* featT = (ushort*)d_ws;          // 2*98*98*64      = 1229312 elems
    ushort* W0p = featT + 1229312;          // 16*19*64*8      = 155648
    ushort* W1p = W0p + 155648;             // 16*8*64*8       = 65536
    ushort* W2p = W1p + 65536;
    ushort* W3p = W2p + 65536;
    ushort* W4p = W3p + 65536;              // 1*8*64*8        = 4096

    prep_feat_k<<<4802, 256, 0, stream>>>(feat, featT);
    prep_w_k<<<76, 256, 0, stream>>>(W0, W0p, 16, 19, 256, 0);
    prep_w_k<<<32, 256, 0, stream>>>(W1, W1p, 16, 8, 256, 1);
    prep_w_k<<<32, 256, 0, stream>>>(W2, W2p, 16, 8, 256, 1);
    prep_w_k<<<32, 256, 0, stream>>>(W3, W3p, 16, 8, 256, 1);
    prep_w_k<<<2, 256, 0, stream>>>(W4, W4p, 1, 8, 1, 2);
    liif_main<<<4096, 256, 0, stream>>>(coord, cell, featT, W0p, W1p, W2p, W3p, W4p,
                                        b0, b1, b2, b3, b4, out);
}

// Round 12
// 195.282 us; speedup vs baseline: 1.2195x; 1.0397x over previous
//
#include <hip/hip_runtime.h>
#include <hip/hip_bf16.h>

typedef __attribute__((ext_vector_type(8))) short bf16x8;
typedef __attribute__((ext_vector_type(4))) float f32x4;

__device__ inline ushort f2bf(float f) {
    union { float f; unsigned u; } x; x.f = f;
    unsigned u = x.u;
    u += 0x7fffu + ((u >> 16) & 1u);   // round-to-nearest-even
    return (ushort)(u >> 16);
}

// feat (B,C,H,W) f32 -> featT (B,98,98,C) bf16, zero-padded 1-px border
__global__ void prep_feat_k(const float* __restrict__ feat, ushort* __restrict__ featT) {
    int idx = blockIdx.x * 256 + threadIdx.x;
    if (idx >= 2 * 98 * 98 * 64) return;
    int c = idx & 63;
    int rest = idx >> 6;
    int x = rest % 98; rest /= 98;
    int y = rest % 98;
    int b = rest / 98;
    ushort v = 0;
    if (x >= 1 && x <= 96 && y >= 1 && y <= 96)
        v = f2bf(feat[((b * 64 + c) * 96 + (y - 1)) * 96 + (x - 1)]);
    featT[idx] = v;
}

// Weights f32 (K,N) -> bf16 B-fragment layout [nt][kt][lane][8]
__global__ void prep_w_k(const float* __restrict__ W, ushort* __restrict__ Wp,
                         int NT, int NKT, int Nstride, int mode) {
    int idx = blockIdx.x * 256 + threadIdx.x;
    if (idx >= NT * NKT * 64) return;
    int lane = idx & 63;
    int kt = (idx >> 6) % NKT;
    int nt = idx / (64 * NKT);
    int n = nt * 16 + (lane & 15);
    int kbase = kt * 32 + (lane >> 4) * 8;
    ushort o[8];
    #pragma unroll
    for (int i = 0; i < 8; ++i) {
        int k = kbase + i;
        float v = 0.0f;
        if (mode == 0) {
            if (k < 576) { int tap = k >> 6, c = k & 63; v = W[(c * 9 + tap) * Nstride + n]; }
            else if (k < 580) v = W[k * Nstride + n];
        } else if (mode == 1) {
            v = W[k * Nstride + n];
        } else {
            v = (n == 0) ? W[k] : 0.0f;
        }
        o[i] = f2bf(v);
    }
    *reinterpret_cast<uint4*>(Wp + (size_t)idx * 8) = *reinterpret_cast<const uint4*>(o);
}

// Activations in MFMA A-fragment layout: line = rt*8+kt, position p=lane.
// Physical slot = p ^ ((p>>4)&3)  (round-9 measured: conflicts 10.9M -> 2.5M).
__device__ __forceinline__ int SW(int p) { return p ^ ((p >> 4) & 3); }

__global__ __launch_bounds__(256, 3) void liif_main(
    const float* __restrict__ coord, const float* __restrict__ cell,
    const ushort* __restrict__ featT,
    const ushort* __restrict__ W0p, const ushort* __restrict__ W1p,
    const ushort* __restrict__ W2p, const ushort* __restrict__ W3p,
    const ushort* __restrict__ W4p,
    const float* __restrict__ b0, const float* __restrict__ b1,
    const float* __restrict__ b2, const float* __restrict__ b3,
    const float* __restrict__ b4, float* __restrict__ out)
{
    // act layout: ((rt*8 + kt)*64 + phys)*8   rt 0..3, kt 0..7   (32768 B)
    __shared__ ushort buf[4 * 8 * 64 * 8];
    __shared__ float pred_lds[64];
    __shared__ float area_lds[64];

    const int t = threadIdx.x;
    const int lane = t & 63;
    const int w = t >> 6;
    const int g = lane >> 4;
    const int l15 = lane & 15;
    const int swl = SW(lane);

    // ---------------- gather setup: minimal persistent state ----------------
    const ushort* p0;
    ushort* g_lds;
    uint ex01, ex23;
    {
        const int r = t >> 2, sub = t & 3;          // r 0..63
        const int qi = r >> 2, s = r & 3;           // row = 4*qi + shift s
        const int gq = blockIdx.x * 16 + qi;        // = b*Q + q
        const int bidx = gq >> 15;                  // Q = 32768
        const float vx = (s & 2) ? 1.0f : -1.0f;
        const float vy = (s & 1) ? 1.0f : -1.0f;
        const float rxf = (float)(1.0 / 96.0);
        const float lo = (float)(-1.0 + 1e-6);
        const float hi = (float)(1.0 - 1e-6);
        float c0 = coord[gq * 2 + 0], c1 = coord[gq * 2 + 1];
        float cl0 = cell[gq * 2 + 0], cl1 = cell[gq * 2 + 1];
        float sc0 = fminf(fmaxf(__fadd_rn(__fadd_rn(c0, vx * rxf), 1e-6f), lo), hi);
        float sc1 = fminf(fmaxf(__fadd_rn(__fadd_rn(c1, vy * rxf), 1e-6f), lo), hi);
        float fy = __fmul_rn(__fadd_rn(__fmul_rn(__fadd_rn(sc0, 1.0f), 96.0f), -1.0f), 0.5f);
        float fx = __fmul_rn(__fadd_rn(__fmul_rn(__fadd_rn(sc1, 1.0f), 96.0f), -1.0f), 0.5f);
        int iy = (int)rintf(fy); iy = iy < 0 ? 0 : (iy > 95 ? 95 : iy);
        int ix = (int)rintf(fx); ix = ix < 0 ? 0 : (ix > 95 ? 95 : ix);
        float qc0 = (iy + 0.5f) * (float)(2.0 / 96.0) - 1.0f;
        float qc1 = (ix + 0.5f) * (float)(2.0 / 96.0) - 1.0f;
        float rel0 = (c0 - qc0) * 96.0f;
        float rel1 = (c1 - qc1) * 96.0f;
        if (sub == 0) {
            area_lds[r] = fabsf(rel0 * rel1) + 1e-9f;
            asm("v_cvt_pk_bf16_f32 %0, %1, %2" : "=v"(ex01) : "v"(rel0), "v"(rel1));
            float rc0 = cl0 * 96.0f, rc1 = cl1 * 96.0f;
            asm("v_cvt_pk_bf16_f32 %0, %1, %2" : "=v"(ex23) : "v"(rc0), "v"(rc1));
        } else {
            ex01 = 0; ex23 = 0;
        }
        const int g_rt = r >> 4;
        const int g_sw = SW((r & 15) + (sub << 4));
        p0 = featT + (size_t)bidx * 98 * 98 * 64 + (iy * 98 + ix) * 64 + sub * 8;
        g_lds = buf + (g_rt * 8 * 64 + g_sw) * 8;   // + LINE*512 immediates
    }

    // act-store bases: value v_j of frag (rt,ct) -> phys 4g + 16m + (j2^hi8),
    // m = 2(ct&1)+hi8, j2 = j^(2(ct&1)); even j2 -> spE, odd -> spO.
    const int hi8 = l15 >> 3;
    ushort* sp  = buf + w * 1024 + g * 32 + hi8 * 128 + (l15 & 7);
    ushort* spE = sp + 8 * hi8;
    ushort* spO = sp - 8 * hi8;

    f32x4 acc[4][4];

    auto store_acts = [&]() {
        #pragma unroll
        for (int ct = 0; ct < 4; ++ct)
            #pragma unroll
            for (int rt = 0; rt < 4; ++rt) {
                float v0 = fmaxf(acc[rt][ct][0], 0.0f);
                float v1 = fmaxf(acc[rt][ct][1], 0.0f);
                float v2 = fmaxf(acc[rt][ct][2], 0.0f);
                float v3 = fmaxf(acc[rt][ct][3], 0.0f);
                uint p01, p23;
                asm("v_cvt_pk_bf16_f32 %0, %1, %2" : "=v"(p01) : "v"(v0), "v"(v1));
                asm("v_cvt_pk_bf16_f32 %0, %1, %2" : "=v"(p23) : "v"(v2), "v"(v3));
                const int off = rt * 4096 + (ct >> 1) * 512 + (ct & 1) * 256;
                if ((ct & 1) == 0) {
                    spE[off + 0]  = (ushort)p01;
                    spO[off + 8]  = (ushort)(p01 >> 16);
                    spE[off + 16] = (ushort)p23;
                    spO[off + 24] = (ushort)(p23 >> 16);
                } else {
                    spE[off + 16] = (ushort)p01;
                    spO[off + 24] = (ushort)(p01 >> 16);
                    spE[off + 0]  = (ushort)p23;
                    spO[off + 8]  = (ushort)(p23 >> 16);
                }
            }
    };

    auto init_acc = [&](const float* bias) {
        #pragma unroll
        for (int ct = 0; ct < 4; ++ct) {
            float bv = bias[(w * 4 + ct) * 16 + l15];
            #pragma unroll
            for (int rt = 0; rt < 4; ++rt) {
                acc[rt][ct][0] = bv; acc[rt][ct][1] = bv;
                acc[rt][ct][2] = bv; acc[rt][ct][3] = bv;
            }
        }
    };

#define LOADW0(DST, KT) do { _Pragma("unroll")                                   \
        for (int ct_ = 0; ct_ < 4; ++ct_)                                        \
            DST[ct_] = *reinterpret_cast<const bf16x8*>(                         \
                W0p + (((size_t)(w * 4 + ct_) * 19 + (KT)) * 64 + lane) * 8);    \
    } while (0)
#define LOADWX(DST, WP, KT) do { _Pragma("unroll")                               \
        for (int ct_ = 0; ct_ < 4; ++ct_)                                        \
            DST[ct_] = *reinterpret_cast<const bf16x8*>(                         \
                (WP) + (((size_t)(w * 4 + ct_) * 8 + (KT)) * 64 + lane) * 8);    \
    } while (0)
#define MFMA_LINE(BFR, LINE) do { _Pragma("unroll")                              \
        for (int rt_ = 0; rt_ < 4; ++rt_) {                                      \
            bf16x8 a_ = *reinterpret_cast<const bf16x8*>(                        \
                buf + ((rt_ * 8 + (LINE)) * 64 + swl) * 8);                      \
            _Pragma("unroll")                                                    \
            for (int ct_ = 0; ct_ < 4; ++ct_)                                    \
                acc[rt_][ct_] = __builtin_amdgcn_mfma_f32_16x16x32_bf16(         \
                    a_, BFR[ct_], acc[rt_][ct_], 0, 0, 0);                       \
        } } while (0)
#define G1(KT, LINE) do {                                                        \
        constexpr int tap_ = (KT) >> 1;                                          \
        constexpr int coff_ = ((tap_ / 3) * 98 + (tap_ % 3)) * 64 + ((KT) & 1) * 32; \
        *reinterpret_cast<uint4*>(g_lds + (LINE) * 512) =                        \
            *reinterpret_cast<const uint4*>(p0 + coff_);                         \
    } while (0)

    // ------- layer 1: 3 phases (8+8+3 k-tiles), 2x-unrolled wA/wB ping-pong, no copies -------
    init_acc(b0);
    bf16x8 wA[4], wB[4];
    G1(0, 0); G1(1, 1); G1(2, 2); G1(3, 3); G1(4, 4); G1(5, 5); G1(6, 6); G1(7, 7);
    LOADW0(wA, 0); LOADW0(wB, 1);
    __syncthreads();
    __builtin_amdgcn_s_setprio(1);
    #pragma unroll 1
    for (int i = 0; i < 8; i += 2) {
        MFMA_LINE(wA, i);     LOADW0(wA, i + 2);   // last iter preloads kt 8 (phase 2)
        MFMA_LINE(wB, i + 1); LOADW0(wB, i + 3);   // last iter preloads kt 9
    }
    __builtin_amdgcn_s_setprio(0);
    __syncthreads();
    G1(8, 0); G1(9, 1); G1(10, 2); G1(11, 3); G1(12, 4); G1(13, 5); G1(14, 6); G1(15, 7);
    __syncthreads();
    __builtin_amdgcn_s_setprio(1);
    #pragma unroll 1
    for (int i = 0; i < 8; i += 2) {
        MFMA_LINE(wA, i);     LOADW0(wA, i + 10);  // last iter preloads kt 16 (phase 3)
        MFMA_LINE(wB, i + 1); LOADW0(wB, i + 11);  // last iter preloads kt 17
    }
    __builtin_amdgcn_s_setprio(0);
    __syncthreads();
    G1(16, 0); G1(17, 1);
    *reinterpret_cast<uint4*>(g_lds + 2 * 512) = make_uint4(ex01, ex23, 0, 0);
    __syncthreads();
    __builtin_amdgcn_s_setprio(1);
    MFMA_LINE(wA, 0); LOADW0(wA, 18);
    MFMA_LINE(wB, 1);
    MFMA_LINE(wA, 2);
    __builtin_amdgcn_s_setprio(0);
    __syncthreads();

    // ---------------- layers 2..4: store -> own-kt mfma -> barrier -> rest ----------------
    #pragma unroll 1
    for (int layer = 0; layer < 3; ++layer) {
        store_acts();
        const ushort* Wp = (layer == 0) ? W1p : (layer == 1) ? W2p : W3p;
        const float* bias = (layer == 0) ? b1 : (layer == 1) ? b2 : b3;
        init_acc(bias);
        const int k0 = 2 * w;
        // own col-tiles provide A for kt = 2w, 2w+1: same-wave DS order makes
        // own write->read safe; overlaps other waves' stores
        LOADWX(wA, Wp, k0);
        __builtin_amdgcn_s_setprio(1);
        LOADWX(wB, Wp, k0 + 1);
        MFMA_LINE(wA, k0);     LOADWX(wA, Wp, (k0 + 2) & 7);
        MFMA_LINE(wB, k0 + 1); LOADWX(wB, Wp, (k0 + 3) & 7);
        __builtin_amdgcn_s_setprio(0);
        __syncthreads();
        __builtin_amdgcn_s_setprio(1);
        MFMA_LINE(wA, (k0 + 2) & 7); LOADWX(wA, Wp, (k0 + 4) & 7);
        MFMA_LINE(wB, (k0 + 3) & 7); LOADWX(wB, Wp, (k0 + 5) & 7);
        MFMA_LINE(wA, (k0 + 4) & 7); LOADWX(wA, Wp, (k0 + 6) & 7);
        MFMA_LINE(wB, (k0 + 5) & 7); LOADWX(wB, Wp, (k0 + 7) & 7);
        MFMA_LINE(wA, (k0 + 6) & 7);
        MFMA_LINE(wB, (k0 + 7) & 7);
        __builtin_amdgcn_s_setprio(0);
        __syncthreads();
    }
    // layer-4 acts
    store_acts();
    __syncthreads();

    // ---------------- layer 5: 256 -> 1 (wave w handles row-tile w) ----------------
    {
        float b4v = b4[0];
        f32x4 a5;
        a5[0] = b4v; a5[1] = b4v; a5[2] = b4v; a5[3] = b4v;
        #pragma unroll
        for (int kt = 0; kt < 8; ++kt) {
            bf16x8 bb = *reinterpret_cast<const bf16x8*>(W4p + ((size_t)kt * 64 + lane) * 8);
            bf16x8 aa = *reinterpret_cast<const bf16x8*>(buf + ((w * 8 + kt) * 64 + swl) * 8);
            a5 = __builtin_amdgcn_mfma_f32_16x16x32_bf16(aa, bb, a5, 0, 0, 0);
        }
        if (l15 == 0) {
            #pragma unroll
            for (int j = 0; j < 4; ++j)
                pred_lds[w * 16 + (g << 2) + j] = a5[j];
        }
    }
    __syncthreads();

    // ---------------- local-ensemble combine (diagonal area swap) ----------------
    if (t < 16) {
        int oq = blockIdx.x * 16 + t;
        float p0v = pred_lds[t * 4 + 0], p1v = pred_lds[t * 4 + 1];
        float p2v = pred_lds[t * 4 + 2], p3v = pred_lds[t * 4 + 3];
        float a0 = area_lds[t * 4 + 0], a1 = area_lds[t * 4 + 1];
        float a2 = area_lds[t * 4 + 2], a3 = area_lds[t * 4 + 3];
        float tot = a0 + a1 + a2 + a3;
        out[oq] = (p0v * a3 + p1v * a2 + p2v * a1 + p3v * a0) / tot;
    }
#undef G1
#undef LOADW0
#undef LOADWX
#undef MFMA_LINE
}

extern "C" void kernel_launch(void* const* d_in, const int* in_sizes, int n_in,
                              void* d_out, int out_size, void* d_ws, size_t ws_size,
                              hipStream_t stream) {
    const float* feat  = (const float*)d_in[0];
    const float* coord = (const float*)d_in[1];
    const float* cell  = (const float*)d_in[2];
    const float* W0 = (const float*)d_in[3];
    const float* b0 = (const float*)d_in[4];
    const float* W1 = (const float*)d_in[5];
    const float* b1 = (const float*)d_in[6];
    const float* W2 = (const float*)d_in[7];
    const float* b2 = (const float*)d_in[8];
    const float* W3 = (const float*)d_in[9];
    const float* b3 = (const float*)d_in[10];
    const float* W4 = (const float*)d_in[11];
    const float* b4 = (const float*)d_in[12];
    float* out = (float*)d_out;

    ushort* featT = (ushort*)d_ws;          // 2*98*98*64      = 1229312 elems
    ushort* W0p = featT + 1229312;          // 16*19*64*8      = 155648
    ushort* W1p = W0p + 155648;             // 16*8*64*8       = 65536
    ushort* W2p = W1p + 65536;
    ushort* W3p = W2p + 65536;
    ushort* W4p = W3p + 65536;              // 1*8*64*8        = 4096

    prep_feat_k<<<4802, 256, 0, stream>>>(feat, featT);
    prep_w_k<<<76, 256, 0, stream>>>(W0, W0p, 16, 19, 256, 0);
    prep_w_k<<<32, 256, 0, stream>>>(W1, W1p, 16, 8, 256, 1);
    prep_w_k<<<32, 256, 0, stream>>>(W2, W2p, 16, 8, 256, 1);
    prep_w_k<<<32, 256, 0, stream>>>(W3, W3p, 16, 8, 256, 1);
    prep_w_k<<<2, 256, 0, stream>>>(W4, W4p, 1, 8, 1, 2);
    liif_main<<<4096, 256, 0, stream>>>(coord, cell, featT, W0p, W1p, W2p, W3p, W4p,
                                        b0, b1, b2, b3, b4, out);
}

// Round 13
// 176.219 us; speedup vs baseline: 1.3514x; 1.1082x over previous
//
#include <hip/hip_runtime.h>
#include <hip/hip_bf16.h>

typedef __attribute__((ext_vector_type(8))) short bf16x8;
typedef __attribute__((ext_vector_type(4))) float f32x4;

__device__ inline ushort f2bf(float f) {
    union { float f; unsigned u; } x; x.f = f;
    unsigned u = x.u;
    u += 0x7fffu + ((u >> 16) & 1u);   // round-to-nearest-even
    return (ushort)(u >> 16);
}

// Weights f32 (K,N) -> bf16 B-fragment layout [nt][kt][lane][8]
__device__ __forceinline__ void pack_w(const float* __restrict__ W, ushort* __restrict__ Wp,
                                       int idx, int NKT, int Nstride, int mode) {
    int lane = idx & 63;
    int kt = (idx >> 6) % NKT;
    int nt = idx / (64 * NKT);
    int n = nt * 16 + (lane & 15);
    int kbase = kt * 32 + (lane >> 4) * 8;
    ushort o[8];
    #pragma unroll
    for (int i = 0; i < 8; ++i) {
        int k = kbase + i;
        float v = 0.0f;
        if (mode == 0) {
            if (k < 576) { int tap = k >> 6, c = k & 63; v = W[(c * 9 + tap) * Nstride + n]; }
            else if (k < 580) v = W[k * Nstride + n];
        } else if (mode == 1) {
            v = W[k * Nstride + n];
        } else {
            v = (n == 0) ? W[k] : 0.0f;
        }
        o[i] = f2bf(v);
    }
    *reinterpret_cast<uint4*>(Wp + (size_t)idx * 8) = *reinterpret_cast<const uint4*>(o);
}

// ONE fused prep dispatch: featT transpose (blocks 0..4801) + all 5 W packs.
__global__ void prep_all_k(const float* __restrict__ feat,
                           const float* __restrict__ W0, const float* __restrict__ W1,
                           const float* __restrict__ W2, const float* __restrict__ W3,
                           const float* __restrict__ W4,
                           ushort* __restrict__ featT,
                           ushort* __restrict__ W0p, ushort* __restrict__ W1p,
                           ushort* __restrict__ W2p, ushort* __restrict__ W3p,
                           ushort* __restrict__ W4p) {
    int bid = blockIdx.x;
    if (bid < 4802) {
        // feat (B,C,H,W) f32 -> featT (B,98,98,C) bf16, zero-padded 1-px border
        int idx = bid * 256 + threadIdx.x;
        if (idx >= 2 * 98 * 98 * 64) return;
        int c = idx & 63;
        int rest = idx >> 6;
        int x = rest % 98; rest /= 98;
        int y = rest % 98;
        int b = rest / 98;
        ushort v = 0;
        if (x >= 1 && x <= 96 && y >= 1 && y <= 96)
            v = f2bf(feat[((b * 64 + c) * 96 + (y - 1)) * 96 + (x - 1)]);
        featT[idx] = v;
    } else if (bid < 4878) {
        int idx = (bid - 4802) * 256 + threadIdx.x;
        if (idx < 16 * 19 * 64) pack_w(W0, W0p, idx, 19, 256, 0);
    } else if (bid < 4910) {
        int idx = (bid - 4878) * 256 + threadIdx.x;
        if (idx < 16 * 8 * 64) pack_w(W1, W1p, idx, 8, 256, 1);
    } else if (bid < 4942) {
        int idx = (bid - 4910) * 256 + threadIdx.x;
        if (idx < 16 * 8 * 64) pack_w(W2, W2p, idx, 8, 256, 1);
    } else if (bid < 4974) {
        int idx = (bid - 4942) * 256 + threadIdx.x;
        if (idx < 16 * 8 * 64) pack_w(W3, W3p, idx, 8, 256, 1);
    } else {
        int idx = (bid - 4974) * 256 + threadIdx.x;
        if (idx < 1 * 8 * 64) pack_w(W4, W4p, idx, 8, 1, 2);
    }
}

// Activations in MFMA A-fragment layout: line = rt*8+kt, position p=lane.
// Physical slot = p ^ ((p>>4)&3)  (round-9 measured: conflicts 10.9M -> 2.5M).
__device__ __forceinline__ int SW(int p) { return p ^ ((p >> 4) & 3); }

__global__ __launch_bounds__(256, 3) void liif_main(
    const float* __restrict__ coord, const float* __restrict__ cell,
    const ushort* __restrict__ featT,
    const ushort* __restrict__ W0p, const ushort* __restrict__ W1p,
    const ushort* __restrict__ W2p, const ushort* __restrict__ W3p,
    const ushort* __restrict__ W4p,
    const float* __restrict__ b0, const float* __restrict__ b1,
    const float* __restrict__ b2, const float* __restrict__ b3,
    const float* __restrict__ b4, float* __restrict__ out)
{
    // act layout: ((rt*8 + kt)*64 + phys)*8   rt 0..3, kt 0..7   (32768 B)
    __shared__ ushort buf[4 * 8 * 64 * 8];
    __shared__ float pred_lds[64];
    __shared__ float area_lds[64];

    const int t = threadIdx.x;
    const int lane = t & 63;
    const int w = t >> 6;
    const int g = lane >> 4;
    const int l15 = lane & 15;
    const int swl = SW(lane);

    // ---------------- gather setup: minimal persistent state ----------------
    const ushort* p0;
    ushort* g_lds;
    uint ex01, ex23;
    {
        const int r = t >> 2, sub = t & 3;          // r 0..63
        const int qi = r >> 2, s = r & 3;           // row = 4*qi + shift s
        const int gq = blockIdx.x * 16 + qi;        // = b*Q + q
        const int bidx = gq >> 15;                  // Q = 32768
        const float vx = (s & 2) ? 1.0f : -1.0f;
        const float vy = (s & 1) ? 1.0f : -1.0f;
        const float rxf = (float)(1.0 / 96.0);
        const float lo = (float)(-1.0 + 1e-6);
        const float hi = (float)(1.0 - 1e-6);
        float c0 = coord[gq * 2 + 0], c1 = coord[gq * 2 + 1];
        float cl0 = cell[gq * 2 + 0], cl1 = cell[gq * 2 + 1];
        float sc0 = fminf(fmaxf(__fadd_rn(__fadd_rn(c0, vx * rxf), 1e-6f), lo), hi);
        float sc1 = fminf(fmaxf(__fadd_rn(__fadd_rn(c1, vy * rxf), 1e-6f), lo), hi);
        float fy = __fmul_rn(__fadd_rn(__fmul_rn(__fadd_rn(sc0, 1.0f), 96.0f), -1.0f), 0.5f);
        float fx = __fmul_rn(__fadd_rn(__fmul_rn(__fadd_rn(sc1, 1.0f), 96.0f), -1.0f), 0.5f);
        int iy = (int)rintf(fy); iy = iy < 0 ? 0 : (iy > 95 ? 95 : iy);
        int ix = (int)rintf(fx); ix = ix < 0 ? 0 : (ix > 95 ? 95 : ix);
        float qc0 = (iy + 0.5f) * (float)(2.0 / 96.0) - 1.0f;
        float qc1 = (ix + 0.5f) * (float)(2.0 / 96.0) - 1.0f;
        float rel0 = (c0 - qc0) * 96.0f;
        float rel1 = (c1 - qc1) * 96.0f;
        if (sub == 0) {
            area_lds[r] = fabsf(rel0 * rel1) + 1e-9f;
            asm("v_cvt_pk_bf16_f32 %0, %1, %2" : "=v"(ex01) : "v"(rel0), "v"(rel1));
            float rc0 = cl0 * 96.0f, rc1 = cl1 * 96.0f;
            asm("v_cvt_pk_bf16_f32 %0, %1, %2" : "=v"(ex23) : "v"(rc0), "v"(rc1));
        } else {
            ex01 = 0; ex23 = 0;
        }
        const int g_rt = r >> 4;
        const int g_sw = SW((r & 15) + (sub << 4));
        p0 = featT + (size_t)bidx * 98 * 98 * 64 + (iy * 98 + ix) * 64 + sub * 8;
        g_lds = buf + (g_rt * 8 * 64 + g_sw) * 8;   // + LINE*512 immediates
    }

    // act-store bases: value v_j of frag (rt,ct) -> phys 4g + 16m + (j2^hi8),
    // m = 2(ct&1)+hi8, j2 = j^(2(ct&1)); even j2 -> spE, odd -> spO.
    const int hi8 = l15 >> 3;
    ushort* sp  = buf + w * 1024 + g * 32 + hi8 * 128 + (l15 & 7);
    ushort* spE = sp + 8 * hi8;
    ushort* spO = sp - 8 * hi8;

    f32x4 acc[4][4];

    auto store_acts = [&]() {
        #pragma unroll
        for (int ct = 0; ct < 4; ++ct)
            #pragma unroll
            for (int rt = 0; rt < 4; ++rt) {
                float v0 = fmaxf(acc[rt][ct][0], 0.0f);
                float v1 = fmaxf(acc[rt][ct][1], 0.0f);
                float v2 = fmaxf(acc[rt][ct][2], 0.0f);
                float v3 = fmaxf(acc[rt][ct][3], 0.0f);
                uint p01, p23;
                asm("v_cvt_pk_bf16_f32 %0, %1, %2" : "=v"(p01) : "v"(v0), "v"(v1));
                asm("v_cvt_pk_bf16_f32 %0, %1, %2" : "=v"(p23) : "v"(v2), "v"(v3));
                const int off = rt * 4096 + (ct >> 1) * 512 + (ct & 1) * 256;
                if ((ct & 1) == 0) {
                    spE[off + 0]  = (ushort)p01;
                    spO[off + 8]  = (ushort)(p01 >> 16);
                    spE[off + 16] = (ushort)p23;
                    spO[off + 24] = (ushort)(p23 >> 16);
                } else {
                    spE[off + 16] = (ushort)p01;
                    spO[off + 24] = (ushort)(p01 >> 16);
                    spE[off + 0]  = (ushort)p23;
                    spO[off + 8]  = (ushort)(p23 >> 16);
                }
            }
    };

    auto init_acc = [&](const float* bias) {
        #pragma unroll
        for (int ct = 0; ct < 4; ++ct) {
            float bv = bias[(w * 4 + ct) * 16 + l15];
            #pragma unroll
            for (int rt = 0; rt < 4; ++rt) {
                acc[rt][ct][0] = bv; acc[rt][ct][1] = bv;
                acc[rt][ct][2] = bv; acc[rt][ct][3] = bv;
            }
        }
    };

#define LOADW0(DST, KT) do { _Pragma("unroll")                                   \
        for (int ct_ = 0; ct_ < 4; ++ct_)                                        \
            DST[ct_] = *reinterpret_cast<const bf16x8*>(                         \
                W0p + (((size_t)(w * 4 + ct_) * 19 + (KT)) * 64 + lane) * 8);    \
    } while (0)
#define LOADWX(DST, WP, KT) do { _Pragma("unroll")                               \
        for (int ct_ = 0; ct_ < 4; ++ct_)                                        \
            DST[ct_] = *reinterpret_cast<const bf16x8*>(                         \
                (WP) + (((size_t)(w * 4 + ct_) * 8 + (KT)) * 64 + lane) * 8);    \
    } while (0)
#define MFMA_LINE(BFR, LINE) do { _Pragma("unroll")                              \
        for (int rt_ = 0; rt_ < 4; ++rt_) {                                      \
            bf16x8 a_ = *reinterpret_cast<const bf16x8*>(                        \
                buf + ((rt_ * 8 + (LINE)) * 64 + swl) * 8);                      \
            _Pragma("unroll")                                                    \
            for (int ct_ = 0; ct_ < 4; ++ct_)                                    \
                acc[rt_][ct_] = __builtin_amdgcn_mfma_f32_16x16x32_bf16(         \
                    a_, BFR[ct_], acc[rt_][ct_], 0, 0, 0);                       \
        } } while (0)
#define G1(KT, LINE) do {                                                        \
        constexpr int tap_ = (KT) >> 1;                                          \
        constexpr int coff_ = ((tap_ / 3) * 98 + (tap_ % 3)) * 64 + ((KT) & 1) * 32; \
        *reinterpret_cast<uint4*>(g_lds + (LINE) * 512) =                        \
            *reinterpret_cast<const uint4*>(p0 + coff_);                         \
    } while (0)

    // ------- layer 1: 3 phases (8+8+3 k-tiles), 2x-unrolled wA/wB ping-pong, no copies -------
    init_acc(b0);
    bf16x8 wA[4], wB[4];
    G1(0, 0); G1(1, 1); G1(2, 2); G1(3, 3); G1(4, 4); G1(5, 5); G1(6, 6); G1(7, 7);
    LOADW0(wA, 0); LOADW0(wB, 1);
    __syncthreads();
    __builtin_amdgcn_s_setprio(1);
    #pragma unroll 1
    for (int i = 0; i < 8; i += 2) {
        MFMA_LINE(wA, i);     LOADW0(wA, i + 2);   // last iter preloads kt 8 (phase 2)
        MFMA_LINE(wB, i + 1); LOADW0(wB, i + 3);   // last iter preloads kt 9
    }
    __builtin_amdgcn_s_setprio(0);
    __syncthreads();
    G1(8, 0); G1(9, 1); G1(10, 2); G1(11, 3); G1(12, 4); G1(13, 5); G1(14, 6); G1(15, 7);
    __syncthreads();
    __builtin_amdgcn_s_setprio(1);
    #pragma unroll 1
    for (int i = 0; i < 8; i += 2) {
        MFMA_LINE(wA, i);     LOADW0(wA, i + 10);  // last iter preloads kt 16 (phase 3)
        MFMA_LINE(wB, i + 1); LOADW0(wB, i + 11);  // last iter preloads kt 17
    }
    __builtin_amdgcn_s_setprio(0);
    __syncthreads();
    G1(16, 0); G1(17, 1);
    *reinterpret_cast<uint4*>(g_lds + 2 * 512) = make_uint4(ex01, ex23, 0, 0);
    __syncthreads();
    __builtin_amdgcn_s_setprio(1);
    MFMA_LINE(wA, 0); LOADW0(wA, 18);
    MFMA_LINE(wB, 1);
    MFMA_LINE(wA, 2);
    __builtin_amdgcn_s_setprio(0);
    __syncthreads();

    // ---------------- layers 2..4: store -> own-kt mfma -> barrier -> rest ----------------
    #pragma unroll 1
    for (int layer = 0; layer < 3; ++layer) {
        store_acts();
        const ushort* Wp = (layer == 0) ? W1p : (layer == 1) ? W2p : W3p;
        const float* bias = (layer == 0) ? b1 : (layer == 1) ? b2 : b3;
        init_acc(bias);
        const int k0 = 2 * w;
        // own col-tiles provide A for kt = 2w, 2w+1: same-wave DS order makes
        // own write->read safe; overlaps other waves' stores
        LOADWX(wA, Wp, k0);
        __builtin_amdgcn_s_setprio(1);
        LOADWX(wB, Wp, k0 + 1);
        MFMA_LINE(wA, k0);     LOADWX(wA, Wp, (k0 + 2) & 7);
        MFMA_LINE(wB, k0 + 1); LOADWX(wB, Wp, (k0 + 3) & 7);
        __builtin_amdgcn_s_setprio(0);
        __syncthreads();
        __builtin_amdgcn_s_setprio(1);
        MFMA_LINE(wA, (k0 + 2) & 7); LOADWX(wA, Wp, (k0 + 4) & 7);
        MFMA_LINE(wB, (k0 + 3) & 7); LOADWX(wB, Wp, (k0 + 5) & 7);
        MFMA_LINE(wA, (k0 + 4) & 7); LOADWX(wA, Wp, (k0 + 6) & 7);
        MFMA_LINE(wB, (k0 + 5) & 7); LOADWX(wB, Wp, (k0 + 7) & 7);
        MFMA_LINE(wA, (k0 + 6) & 7);
        MFMA_LINE(wB, (k0 + 7) & 7);
        __builtin_amdgcn_s_setprio(0);
        __syncthreads();
    }
    // layer-4 acts
    store_acts();
    __syncthreads();

    // ---------------- layer 5: 256 -> 1 (wave w handles row-tile w) ----------------
    {
        float b4v = b4[0];
        f32x4 a5;
        a5[0] = b4v; a5[1] = b4v; a5[2] = b4v; a5[3] = b4v;
        #pragma unroll
        for (int kt = 0; kt < 8; ++kt) {
            bf16x8 bb = *reinterpret_cast<const bf16x8*>(W4p + ((size_t)kt * 64 + lane) * 8);
            bf16x8 aa = *reinterpret_cast<const bf16x8*>(buf + ((w * 8 + kt) * 64 + swl) * 8);
            a5 = __builtin_amdgcn_mfma_f32_16x16x32_bf16(aa, bb, a5, 0, 0, 0);
        }
        if (l15 == 0) {
            #pragma unroll
            for (int j = 0; j < 4; ++j)
                pred_lds[w * 16 + (g << 2) + j] = a5[j];
        }
    }
    __syncthreads();

    // ---------------- local-ensemble combine (diagonal area swap) ----------------
    if (t < 16) {
        int oq = blockIdx.x * 16 + t;
        float p0v = pred_lds[t * 4 + 0], p1v = pred_lds[t * 4 + 1];
        float p2v = pred_lds[t * 4 + 2], p3v = pred_lds[t * 4 + 3];
        float a0 = area_lds[t * 4 + 0], a1 = area_lds[t * 4 + 1];
        float a2 = area_lds[t * 4 + 2], a3 = area_lds[t * 4 + 3];
        float tot = a0 + a1 + a2 + a3;
        out[oq] = (p0v * a3 + p1v * a2 + p2v * a1 + p3v * a0) / tot;
    }
#undef G1
#undef LOADW0
#undef LOADWX
#undef MFMA_LINE
}

extern "C" void kernel_launch(void* const* d_in, const int* in_sizes, int n_in,
                              void* d_out, int out_size, void* d_ws, size_t ws_size,
                              hipStream_t stream) {
    const float* feat  = (const float*)d_in[0];
    const float* coord = (const float*)d_in[1];
    const float* cell  = (const float*)d_in[2];
    const float* W0 = (const float*)d_in[3];
    const float* b0 = (const float*)d_in[4];
    const float* W1 = (const float*)d_in[5];
    const float* b1 = (const float*)d_in[6];
    const float* W2 = (const float*)d_in[7];
    const float* b2 = (const float*)d_in[8];
    const float* W3 = (const float*)d_in[9];
    const float* b3 = (const float*)d_in[10];
    const float* W4 = (const float*)d_in[11];
    const float* b4 = (const float*)d_in[12];
    float* out = (float*)d_out;

    ushort* featT = (ushort*)d_ws;          // 2*98*98*64      = 1229312 elems
    ushort* W0p = featT + 1229312;          // 16*19*64*8      = 155648
    ushort* W1p = W0p + 155648;             // 16*8*64*8       = 65536
    ushort* W2p = W1p + 65536;
    ushort* W3p = W2p + 65536;
    ushort* W4p = W3p + 65536;              // 1*8*64*8        = 4096

    prep_all_k<<<4976, 256, 0, stream>>>(feat, W0, W1, W2, W3, W4,
                                         featT, W0p, W1p, W2p, W3p, W4p);
    liif_main<<<4096, 256, 0, stream>>>(coord, cell, featT, W0p, W1p, W2p, W3p, W4p,
                                        b0, b1, b2, b3, b4, out);
}